// Round 2
// baseline (571.935 us; speedup 1.0000x reference)
//
#include <hip/hip_runtime.h>
#include <hip/hip_bf16.h>
#include <stdint.h>

typedef __bf16 bf16_t;
typedef __bf16 bf16x8 __attribute__((ext_vector_type(8)));
typedef __bf16 bf16x4 __attribute__((ext_vector_type(4)));
typedef float f32x4 __attribute__((ext_vector_type(4)));
typedef unsigned int u32x4 __attribute__((ext_vector_type(4)));

#define MFMA16(A, B, C) __builtin_amdgcn_mfma_f32_16x16x32_bf16(A, B, C, 0, 0, 0)

// async global->LDS, 16B per lane. LDS dest = wave-uniform base + lane*16.
__device__ inline void dma16(const void* g, void* l) {
    __builtin_amdgcn_global_load_lds(
        (const __attribute__((address_space(1))) unsigned int*)g,
        (__attribute__((address_space(3))) unsigned int*)l, 16, 0, 0);
}

__device__ inline unsigned pack2(float a, float b) {
    unsigned short ua = __builtin_bit_cast(unsigned short, (bf16_t)a);
    unsigned short ub = __builtin_bit_cast(unsigned short, (bf16_t)b);
    return (unsigned)ua | ((unsigned)ub << 16);
}

// ---------------------------------------------------------------------------
// fp32 -> bf16 elementwise (8 elems / thread)
// ---------------------------------------------------------------------------
__global__ __launch_bounds__(256)
void cvt_kernel(const float* __restrict__ in, bf16_t* __restrict__ outp, int n8)
{
    int i = blockIdx.x * 256 + threadIdx.x;
    if (i >= n8) return;
    const float* p = in + (size_t)i * 8;
    f32x4 a = *(const f32x4*)p;
    f32x4 b = *(const f32x4*)(p + 4);
    bf16x8 r;
    r[0] = (bf16_t)a[0]; r[1] = (bf16_t)a[1]; r[2] = (bf16_t)a[2]; r[3] = (bf16_t)a[3];
    r[4] = (bf16_t)b[0]; r[5] = (bf16_t)b[1]; r[6] = (bf16_t)b[2]; r[7] = (bf16_t)b[3];
    *(bf16x8*)(outp + (size_t)i * 8) = r;
}

// four 1024x1024 fp32 weights -> one packed bf16 buffer [4][1024][1024]
__global__ __launch_bounds__(256)
void cvt4_kernel(const float* __restrict__ W0, const float* __restrict__ W1,
                 const float* __restrict__ W2, const float* __restrict__ W3,
                 bf16_t* __restrict__ outp)
{
    int i = blockIdx.x * 256 + threadIdx.x;   // 2048 blocks * 256 = 4 * 131072
    int sel = i >> 17;
    int j = i & 131071;
    const float* src = sel == 0 ? W0 : sel == 1 ? W1 : sel == 2 ? W2 : W3;
    const float* p = src + (size_t)j * 8;
    f32x4 a = *(const f32x4*)p;
    f32x4 b = *(const f32x4*)(p + 4);
    bf16x8 r;
    r[0] = (bf16_t)a[0]; r[1] = (bf16_t)a[1]; r[2] = (bf16_t)a[2]; r[3] = (bf16_t)a[3];
    r[4] = (bf16_t)b[0]; r[5] = (bf16_t)b[1]; r[6] = (bf16_t)b[2]; r[7] = (bf16_t)b[3];
    *(bf16x8*)(outp + (size_t)i * 8) = r;   // sel*1M + j*8 == i*8
}

// ---------------------------------------------------------------------------
// GEMM core, 64x128 tile: out[m][n] = sum_k A[m][k]*W[n][k] + bias[n].
// A: M x 1024 bf16, W: 1024 x 1024 bf16 (B^T). global_load_lds staging,
// frag-major lane-linear LDS, double-buffered (2 x 12 KB), 1 barrier/iter.
// 64-row M-tile -> 2x the blocks of the 128 version (latency-bound regime:
// TLP > per-wave MFMA density). mode 0: fp32 out; 1: RoPE bf16; 2: Vt bf16.
// ---------------------------------------------------------------------------
__device__ __forceinline__
void gemm_core64(const bf16_t* __restrict__ A, const bf16_t* __restrict__ W,
                 const float* __restrict__ bias, void* __restrict__ outp,
                 int mode, float scale,
                 const float* __restrict__ sinp, const float* __restrict__ cosp,
                 int m0, int n0, char* lds)
{
    const int K = 1024;
    const int ASZ = 4096, BUF = 12288;
    const int t = threadIdx.x;
    const int w = t >> 6, l = t & 63;
    const int wm = w >> 1, wn = w & 1;
    const int lr = l & 15;          // frag row
    const int kch = (l >> 4) * 8;   // k chunk within BK=32

    const f32x4 zz = {0.f, 0.f, 0.f, 0.f};
    f32x4 acc[2][4];
#pragma unroll
    for (int i = 0; i < 2; i++)
#pragma unroll
        for (int j = 0; j < 4; j++) acc[i][j] = zz;

    // prologue: stage k0=0 into buffer 0 (A frags 0..3: one per wave; B frags 0..7)
    dma16(A + (size_t)(m0 + w * 16 + lr) * K + kch, lds + w * 1024);
#pragma unroll
    for (int i = 0; i < 2; i++) {
        int f = w * 2 + i;
        dma16(W + (size_t)(n0 + f * 16 + lr) * K + kch, lds + ASZ + f * 1024);
    }
    __syncthreads();

    int bo = 0;
    for (int k0 = 0; k0 < K; k0 += 32) {
        int kn = k0 + 32;
        if (kn < K) {                       // prefetch next K-tile
            int nb = bo ^ BUF;
            dma16(A + (size_t)(m0 + w * 16 + lr) * K + kn + kch, lds + nb + w * 1024);
#pragma unroll
            for (int i = 0; i < 2; i++) {
                int f = w * 2 + i;
                dma16(W + (size_t)(n0 + f * 16 + lr) * K + kn + kch, lds + nb + ASZ + f * 1024);
            }
        }
        bf16x8 af[2], bfg[4];
#pragma unroll
        for (int mt = 0; mt < 2; mt++)
            af[mt] = *(const bf16x8*)(lds + bo + ((wm * 2 + mt) * 64 + l) * 16);
#pragma unroll
        for (int nt = 0; nt < 4; nt++)
            bfg[nt] = *(const bf16x8*)(lds + bo + ASZ + ((wn * 4 + nt) * 64 + l) * 16);
#pragma unroll
        for (int mt = 0; mt < 2; mt++)
#pragma unroll
            for (int nt = 0; nt < 4; nt++)
                acc[mt][nt] = MFMA16(af[mt], bfg[nt], acc[mt][nt]);
        __syncthreads();   // drains vmcnt(0): next buffer ready, current reads done
        bo ^= BUF;
    }

    const int quad = l >> 4, lc = l & 15;
#pragma unroll
    for (int mt = 0; mt < 2; mt++) {
#pragma unroll
        for (int nt = 0; nt < 4; nt++) {
            int gn = n0 + wn * 64 + nt * 16 + lc;
            float bv = bias[gn];
            int gm0 = m0 + wm * 32 + mt * 16 + quad * 4;
            if (mode == 0) {
                float* o32 = (float*)outp;
#pragma unroll
                for (int r = 0; r < 4; r++)
                    o32[(size_t)(gm0 + r) * 1024 + gn] = acc[mt][nt][r] + bv;
            } else if (mode == 1) {
                bf16_t* ob = (bf16_t*)outp;
                int h = gn >> 7, d = gn & 127;
#pragma unroll
                for (int r = 0; r < 4; r++) {
                    int gm = gm0 + r;
                    int b = gm / 2304;
                    int pos = gm - b * 2304;
                    float val = acc[mt][nt][r] + bv;
                    float pv = __shfl_xor(val, 1);   // partner d^1 (lane lc^1)
                    float sn = sinp[pos * 128 + d];
                    float cs = cosp[pos * 128 + d];
                    float res = (d & 1) ? (val * cs - pv * sn) : (val * cs + pv * sn);
                    ob[(((size_t)b * 8 + h) * 2304 + pos) * 128 + d] = (bf16_t)(res * scale);
                }
            } else {  // mode 2: Vt (B*nh, 128, 2304)
                bf16_t* ob = (bf16_t*)outp;
                int h = gn >> 7, d = gn & 127;
                int b = gm0 / 2304;
                int pos0 = gm0 - b * 2304;
                bf16x4 s4;
#pragma unroll
                for (int r = 0; r < 4; r++)
                    s4[r] = (bf16_t)(acc[mt][nt][r] + bv);
                *(bf16x4*)(ob + (((size_t)b * 8 + h) * 128 + d) * 2304 + pos0) = s4;
            }
        }
    }
}

__global__ __launch_bounds__(256)
void gemm_bt_kernel(const bf16_t* __restrict__ A, const bf16_t* __restrict__ W,
                    const float* __restrict__ bias, void* __restrict__ outp,
                    int mode, float scale,
                    const float* __restrict__ sinp, const float* __restrict__ cosp)
{
    __shared__ __align__(16) char lds[24576];
    gemm_core64(A, W, bias, outp, mode, scale, sinp, cosp,
                blockIdx.x * 64, blockIdx.y * 128, lds);
}

// Fused Q/K/V projection. blockIdx.y in [0,24): third = y>>3 selects {Q,K,V}.
__global__ __launch_bounds__(256)
void gemm_qkv_kernel(const bf16_t* __restrict__ A, const bf16_t* __restrict__ Wall,
                     const float* __restrict__ bq, const float* __restrict__ bk,
                     const float* __restrict__ bv,
                     void* __restrict__ qb, void* __restrict__ kb, void* __restrict__ vtb,
                     const float* __restrict__ sinp, const float* __restrict__ cosp,
                     float kscale)
{
    __shared__ __align__(16) char lds[24576];
    int ny = blockIdx.y;
    int third = ny >> 3;                 // 0=Q 1=K 2=V (wave-uniform)
    int n0 = (ny & 7) * 128;
    const bf16_t* W = Wall + (size_t)third * 1048576;
    const float* bias = third == 0 ? bq : third == 1 ? bk : bv;
    void* outp = third == 0 ? qb : third == 1 ? kb : vtb;
    int mode = third == 2 ? 2 : 1;
    float scale = third == 1 ? kscale : 1.0f;
    gemm_core64(A, W, bias, outp, mode, scale, sinp, cosp, blockIdx.x * 64, n0, lds);
}

// ---------------------------------------------------------------------------
// Flash attention, transposed scheme, 8-wave kv-split blocks.
// Block = 512 threads: waves 0-3 cover kv [0,1152), waves 4-7 kv [1152,2304),
// both over the same 64 q-rows. Doubles resident waves/SIMD (latency-bound
// regime) and halves the per-block serial chain (18 iters/half vs 36).
// Per half: S^T = MFMA(A=K-frag, B=Q-frag) -> per-lane softmax state,
// P->B-frag via in-register shuffles, PV: MFMA(A=Vt-frag, B=P-frag).
// K/V single-buffered per half (64 KB total), mask reg-prefetched 1 tile ahead.
// End: LDS merge of the two (m, l, O) partials, half-0 waves store.
// Grid is 1D with an XCD pair-swizzle so the b=0/b=1 blocks reading the SAME
// mask region land on the same XCD adjacent in time (mask = dominant stream).
// ---------------------------------------------------------------------------
__global__ __launch_bounds__(512, 4)
void attn_kernel(const bf16_t* __restrict__ q, const bf16_t* __restrict__ k,
                 const bf16_t* __restrict__ vt, const float* __restrict__ mask,
                 bf16_t* __restrict__ o)
{
    const int N = 2304;
    const int HK = 1152;               // kv span per half
    __shared__ __align__(16) char lds[65536];

    const int t = threadIdx.x;
    const int w = t >> 6, l = t & 63;
    const int hv = w >> 2, wl = w & 3;       // kv-half, wave-in-half
    const int quad = l >> 4, lc = l & 15;

    // pair swizzle: ids p and p+8 (same group of 16) -> same XCD (id%8 rule),
    // carry the two b values of one (qblk, h) pair.
    int gid = blockIdx.x;                    // [0, 576)
    int grp = gid >> 4, sub = gid & 15;
    int u = grp * 8 + (sub & 7);             // [0, 288) = 36 qblk x 8 h
    int b = sub >> 3;
    int qblk = u >> 3, h = u & 7;
    int bh = b * 8 + h;
    int q0 = qblk * 64;

    const int qrow = q0 + wl * 16 + lc;

    const bf16_t* qb = q + (size_t)bh * N * 128;
    const bf16_t* kb = k + (size_t)bh * N * 128 + (size_t)hv * HK * 128;
    const bf16_t* vtb = vt + (size_t)bh * 128 * N + hv * HK;
    const float* mq = mask + (size_t)h * N * N + (size_t)qrow * N + hv * HK + quad * 4;

    char* Ks = lds + hv * 32768;
    char* Vts = Ks + 16384;

    bf16x8 qf[4];
#pragma unroll
    for (int kc = 0; kc < 4; kc++)
        qf[kc] = *(const bf16x8*)(qb + (size_t)qrow * 128 + kc * 32 + quad * 8);

    f32x4 mv[4], mvn[4];
#pragma unroll
    for (int nt = 0; nt < 4; nt++)
        mv[nt] = *(const f32x4*)(mq + nt * 16);

    const f32x4 zz = {0.f, 0.f, 0.f, 0.f};
    float Mr = -1e30f, Lr = 0.f;
    f32x4 Oacc[8];
#pragma unroll
    for (int i = 0; i < 8; i++) Oacc[i] = zz;

    for (int kv0 = 0; kv0 < HK; kv0 += 64) {
        __syncthreads();                 // all reads of previous tile done
#pragma unroll
        for (int i = 0; i < 4; i++) {
            int f = wl * 4 + i;
            // K frag (nt=f>>2, kc=f&3): lane -> K[kv0+nt*16+lc][kc*32+quad*8 ..+8]
            dma16(kb + (size_t)(kv0 + (f >> 2) * 16 + lc) * 128 + (f & 3) * 32 + quad * 8,
                  Ks + f * 1024);
            // Vt frag (dt=f>>1, pc=f&1): lane -> Vt[dt*16+lc][kv0+pc*32+quad*8 ..+8]
            dma16(vtb + (size_t)((f >> 1) * 16 + lc) * N + kv0 + (f & 1) * 32 + quad * 8,
                  Vts + f * 1024);
        }
        __syncthreads();                 // staging complete
        int nxt = kv0 + 64;
        if (nxt < HK) {                  // mask prefetch rides under compute
#pragma unroll
            for (int nt = 0; nt < 4; nt++)
                mvn[nt] = *(const f32x4*)(mq + nxt + nt * 16);
        }

        // S^T tile: s[nt][r] = S[qrow][base + kv0 + nt*16 + quad*4 + r] + mask
        f32x4 s[4];
#pragma unroll
        for (int nt = 0; nt < 4; nt++) {
            f32x4 a = zz;
#pragma unroll
            for (int kc = 0; kc < 4; kc++) {
                bf16x8 kf = *(const bf16x8*)(Ks + ((nt * 4 + kc) * 64 + l) * 16);
                a = MFMA16(kf, qf[kc], a);
            }
            s[nt] = a + mv[nt];
        }

        // per-lane online softmax (row = qrow); row lives in lanes lc,+16,+32,+48
        float mx = fmaxf(fmaxf(fmaxf(s[0][0], s[0][1]), fmaxf(s[0][2], s[0][3])),
                         fmaxf(fmaxf(s[1][0], s[1][1]), fmaxf(s[1][2], s[1][3])));
        mx = fmaxf(mx, fmaxf(fmaxf(fmaxf(s[2][0], s[2][1]), fmaxf(s[2][2], s[2][3])),
                             fmaxf(fmaxf(s[3][0], s[3][1]), fmaxf(s[3][2], s[3][3]))));
        mx = fmaxf(mx, __shfl_xor(mx, 16));
        mx = fmaxf(mx, __shfl_xor(mx, 32));
        float mnew = fmaxf(Mr, mx);
        float alpha = __expf(Mr - mnew);
        Mr = mnew;

        float rs = 0.f;
        unsigned pw[4][2];
#pragma unroll
        for (int nt = 0; nt < 4; nt++) {
            float p0 = __expf(s[nt][0] - mnew);
            float p1 = __expf(s[nt][1] - mnew);
            float p2 = __expf(s[nt][2] - mnew);
            float p3 = __expf(s[nt][3] - mnew);
            rs += (p0 + p1) + (p2 + p3);
            pw[nt][0] = pack2(p0, p1);
            pw[nt][1] = pack2(p2, p3);
        }
        rs += __shfl_xor(rs, 16);
        rs += __shfl_xor(rs, 32);
        Lr = Lr * alpha + rs;

#pragma unroll
        for (int dt = 0; dt < 8; dt++)
#pragma unroll
            for (int r = 0; r < 4; r++)
                Oacc[dt][r] *= alpha;

        // P -> B-frag (lane n=lc holds kv = pc*32 + quad*8 + j) via shuffles.
#pragma unroll
        for (int pc = 0; pc < 2; pc++) {
            u32x4 wv;
#pragma unroll
            for (int jp = 0; jp < 4; jp++) {
                int src = ((quad & 1) * 2 + (jp >> 1)) * 16 + lc;
                int t0 = __shfl((int)pw[pc * 2 + 0][jp & 1], src);
                int t1 = __shfl((int)pw[pc * 2 + 1][jp & 1], src);
                wv[jp] = (quad >> 1) ? (unsigned)t1 : (unsigned)t0;
            }
            bf16x8 pf = __builtin_bit_cast(bf16x8, wv);
#pragma unroll
            for (int dt = 0; dt < 8; dt++) {
                bf16x8 vf = *(const bf16x8*)(Vts + ((dt * 2 + pc) * 64 + l) * 16);
                Oacc[dt] = MFMA16(vf, pf, Oacc[dt]);  // O^T: row=d, col=q (=lc)
            }
        }

        if (nxt < HK) {
#pragma unroll
            for (int nt = 0; nt < 4; nt++) mv[nt] = mvn[nt];
        }
    }

    // ---- merge the two kv-halves via LDS (reuses staging space) ----
    __syncthreads();                     // all compute done; LDS free
    float* Ml = (float*)(lds + 32768);
    if (hv == 1) {
        float* ob = (float*)(lds + wl * 8192);
#pragma unroll
        for (int dt = 0; dt < 8; dt++)
            *(f32x4*)(ob + (size_t)(dt * 64 + l) * 4) = Oacc[dt];
        if (quad == 0) {
            Ml[wl * 16 + lc] = Mr;
            Ml[64 + wl * 16 + lc] = Lr;
        }
    }
    __syncthreads();
    if (hv == 0) {
        const float* ob = (const float*)(lds + wl * 8192);
        float M1 = Ml[wl * 16 + lc];
        float L1 = Ml[64 + wl * 16 + lc];
        float M = fmaxf(Mr, M1);
        float w0 = __expf(Mr - M), w1 = __expf(M1 - M);
        float inv = 1.f / (Lr * w0 + L1 * w1);
#pragma unroll
        for (int dt = 0; dt < 8; dt++) {
            f32x4 o1 = *(const f32x4*)(ob + (size_t)(dt * 64 + l) * 4);
            bf16x4 s4;
#pragma unroll
            for (int r = 0; r < 4; r++)
                s4[r] = (bf16_t)((Oacc[dt][r] * w0 + o1[r] * w1) * inv);
            *(bf16x4*)(o + ((size_t)b * N + qrow) * 1024 + h * 128 + dt * 16 + quad * 4) = s4;
        }
    }
}

// ---------------------------------------------------------------------------
// LEPE from Vt: depthwise 5x5 SAME conv + bias (fp32 wgt), + attn output.
// ---------------------------------------------------------------------------
__global__ __launch_bounds__(256)
void lepe_kernel(const bf16_t* __restrict__ vt, const float* __restrict__ wgt,
                 const float* __restrict__ lb, const bf16_t* __restrict__ o,
                 bf16_t* __restrict__ ab)
{
    __shared__ __align__(16) bf16_t sv[5 * 48 * 128];  // 61440 B
    const int bh = blockIdx.y;
    const int b = bh >> 3, h = bh & 7;
    const int y0 = blockIdx.x;
    const int t = threadIdx.x;

#pragma unroll
    for (int it = 0; it < 15; it++) {
        int idx = t + it * 256;           // 0..3839
        int ck = idx % 6;
        int dy = idx / 6;
        int d = dy & 127, yloc = dy >> 7;
        int y = y0 - 2 + yloc;
        bf16x8 vvv;
#pragma unroll
        for (int j = 0; j < 8; j++) vvv[j] = (bf16_t)0.f;
        if (y >= 0 && y < 48)
            vvv = *(const bf16x8*)(vt + ((size_t)bh * 128 + d) * 2304 + y * 48 + ck * 8);
        int x0 = ck * 8;
#pragma unroll
        for (int j = 0; j < 8; j++)
            sv[(yloc * 48 + x0 + j) * 128 + d] = vvv[j];
    }
    __syncthreads();

    const int d0 = (t & 15) * 8;
    const int xb = t >> 4;
    float acc[3][8];
    f32x4 b0 = *(const f32x4*)(lb + h * 128 + d0);
    f32x4 b1 = *(const f32x4*)(lb + h * 128 + d0 + 4);
#pragma unroll
    for (int c = 0; c < 3; c++)
#pragma unroll
        for (int j = 0; j < 4; j++) { acc[c][j] = b0[j]; acc[c][4 + j] = b1[j]; }

#pragma unroll
    for (int ky = 0; ky < 5; ky++) {
#pragma unroll
        for (int kx = 0; kx < 5; kx++) {
            const float* wp = wgt + (size_t)(ky * 5 + kx) * 1024 + h * 128 + d0;
            f32x4 w0 = *(const f32x4*)wp;
            f32x4 w1 = *(const f32x4*)(wp + 4);
#pragma unroll
            for (int c = 0; c < 3; c++) {
                int xx = xb + c * 16 + kx - 2;
                if (xx < 0 || xx >= 48) continue;
                bf16x8 vv = *(const bf16x8*)(&sv[(ky * 48 + xx) * 128 + d0]);
#pragma unroll
                for (int j = 0; j < 4; j++) {
                    acc[c][j]     += (float)vv[j]     * w0[j];
                    acc[c][4 + j] += (float)vv[4 + j] * w1[j];
                }
            }
        }
    }
#pragma unroll
    for (int c = 0; c < 3; c++) {
        int x = xb + c * 16;
        size_t off = ((size_t)b * 2304 + y0 * 48 + x) * 1024 + h * 128 + d0;
        bf16x8 ov = *(const bf16x8*)(o + off);
        bf16x8 res;
#pragma unroll
        for (int j = 0; j < 8; j++) res[j] = (bf16_t)(acc[c][j] + (float)ov[j]);
        *(bf16x8*)(ab + off) = res;
    }
}

// ---------------------------------------------------------------------------
extern "C" void kernel_launch(void* const* d_in, const int* in_sizes, int n_in,
                              void* d_out, int out_size, void* d_ws, size_t ws_size,
                              hipStream_t stream)
{
    const float* x    = (const float*)d_in[0];
    const float* sin_ = (const float*)d_in[1];
    const float* cos_ = (const float*)d_in[2];
    const float* mask = (const float*)d_in[3];
    const float* Wq   = (const float*)d_in[4];
    const float* bq   = (const float*)d_in[5];
    const float* Wk   = (const float*)d_in[6];
    const float* bk   = (const float*)d_in[7];
    const float* Wv   = (const float*)d_in[8];
    const float* bv   = (const float*)d_in[9];
    const float* lw   = (const float*)d_in[10];
    const float* lb   = (const float*)d_in[11];
    const float* Wo   = (const float*)d_in[12];
    const float* bo   = (const float*)d_in[13];

    const size_t NB = (size_t)2 * 2304 * 1024;  // 4,718,592 elems

    // d_out (18.9 MB fp32) doubles as scratch until the final GEMM:
    bf16_t* dout_b = (bf16_t*)d_out;
    bf16_t* x16 = dout_b;          // front half: x in bf16 (dead after QKV gemm)
    bf16_t* vtb = dout_b + NB;     // back half: Vt (B*nh,128,2304) bf16
    bf16_t* ob  = dout_b;          // front half: attn out bf16 (after x16 dead)

    // ws: 27.3 MB of proven-available 28.3 MB
    bf16_t* qb   = (bf16_t*)d_ws;          // (B,nh,N,kd) bf16, 9.44 MB
    bf16_t* kb   = qb + NB;                // (B,nh,N,kd) bf16, 9.44 MB
    bf16_t* wbuf = kb + NB;                // 4M bf16: [Wq|Wk|Wv|Wo], 8 MB
    bf16_t* ab   = qb;                     // lepe out, reuses qb after attention

    dim3 blk(256);
    const float kscale = 0.08838834764831845f;  // 1/sqrt(128)

    cvt_kernel<<<2304, blk, 0, stream>>>(x, x16, 589824);
    cvt4_kernel<<<2048, blk, 0, stream>>>(Wq, Wk, Wv, Wo, wbuf);
    gemm_qkv_kernel<<<dim3(72, 24), blk, 0, stream>>>(x16, wbuf, bq, bk, bv,
                                                      qb, kb, vtb, sin_, cos_, kscale);
    attn_kernel<<<576, dim3(512), 0, stream>>>(qb, kb, vtb, mask, ob);
    lepe_kernel<<<dim3(48, 16), blk, 0, stream>>>(vtb, lw, lb, ob, ab);
    gemm_bt_kernel<<<dim3(72, 8), blk, 0, stream>>>(ab, wbuf + 3 * 1048576, bo,
                                                    d_out, 0, 1.0f, nullptr, nullptr);
}